// Round 12
// baseline (273.199 us; speedup 1.0000x reference)
//
#include <hip/hip_runtime.h>
#include <hip/hip_fp16.h>

constexpr int NN   = 50000;            // nodes
constexpr int NE   = 800000;           // edges (self-loops handled analytically)
constexpr int NG   = 512;              // graphs
constexpr int NLAT = 64;               // latent dim
constexpr float SLOPE = 0.2f;          // leaky relu slope

constexpr int NBK  = 196;              // coarse buckets of 256 nodes
constexpr int BCAP = 8192;             // per-bucket capacity
constexpr int EPB  = 4096;             // edges per pass-1 block
constexpr int NB1  = (NE + EPB - 1) / EPB;   // 196

typedef _Float16 h8 __attribute__((ext_vector_type(8)));
typedef float f32x4 __attribute__((ext_vector_type(4)));

// ============ pass 1: bucket edges by dst>>8 with LDS staging ============
__global__ void p1_bucket(const int* __restrict__ ei, int* __restrict__ gcur,
                          unsigned* __restrict__ gbuf) {
  __shared__ unsigned lin[EPB];
  __shared__ unsigned lout[EPB];
  __shared__ int lhist[NBK], lbase[NBK + 1], lcur[NBK], goff[NBK];
  __shared__ int tmp[256];
  const int tid = threadIdx.x;
  if (tid < NBK) lhist[tid] = 0;
  __syncthreads();
  const int e0 = blockIdx.x * EPB;
#pragma unroll
  for (int i = 0; i < EPB / 256; ++i) {
    int e = e0 + i * 256 + tid;
    unsigned p = 0xFFFFFFFFu;
    if (e < NE) {
      int s = ei[e], d = ei[NE + e];
      p = ((unsigned)(d >> 8) << 24) | ((unsigned)(d & 255) << 16) | (unsigned)s;
      atomicAdd(&lhist[d >> 8], 1);
    }
    lin[i * 256 + tid] = p;
  }
  __syncthreads();
  int v = (tid < NBK) ? lhist[tid] : 0;
  tmp[tid] = v;
  __syncthreads();
  for (int off = 1; off < 256; off <<= 1) {
    int t = (tid >= off) ? tmp[tid - off] : 0;
    __syncthreads();
    tmp[tid] += t;
    __syncthreads();
  }
  if (tid < NBK) { lbase[tid] = tmp[tid] - v; lcur[tid] = tmp[tid] - v; }
  if (tid == NBK - 1) lbase[NBK] = tmp[NBK - 1];
  __syncthreads();
#pragma unroll
  for (int i = 0; i < EPB / 256; ++i) {
    unsigned p = lin[i * 256 + tid];
    if (p != 0xFFFFFFFFu) {
      int b = p >> 24;
      int pos = atomicAdd(&lcur[b], 1);
      lout[pos] = p & 0xFFFFFFu;
    }
  }
  if (tid < NBK) goff[tid] = atomicAdd(&gcur[tid], lhist[tid]);
  __syncthreads();
  const int total = lbase[NBK];
  for (int i = tid; i < total; i += 256) {
    int lo = 0, hi = NBK - 1;
    while (lo < hi) { int mid = (lo + hi + 1) >> 1; if (lbase[mid] <= i) lo = mid; else hi = mid - 1; }
    gbuf[(size_t)lo * BCAP + goff[lo] + (i - lbase[lo])] = lout[i];
  }
}

// ============ pass 2: fused bucket-base scan + per-bucket counting sort ============
__global__ void p2_sort(const unsigned* __restrict__ gbuf, const int* __restrict__ gcur,
                        int* __restrict__ bbase_out, int* __restrict__ rp,
                        unsigned* __restrict__ spk) {
  __shared__ unsigned lin[BCAP];
  __shared__ unsigned lsorted[BCAP];
  __shared__ int lhist[256], lcur2[256], tmp[256], sscan[256];
  const int tid = threadIdx.x;
  const int b = blockIdx.x;
  int gv = (tid < NBK) ? gcur[tid] : 0;
  tmp[tid] = gv;
  __syncthreads();
  for (int off = 1; off < 256; off <<= 1) {
    int t = (tid >= off) ? tmp[tid - off] : 0;
    __syncthreads();
    tmp[tid] += t;
    __syncthreads();
  }
  sscan[tid] = tmp[tid];
  __syncthreads();
  const int base = b ? sscan[b - 1] : 0;
  const int cnt = min(gcur[b], BCAP);
  if (tid == 0) { bbase_out[b] = base; if (b == 0) rp[NN] = NE; }
  lhist[tid] = 0;
  __syncthreads();
  for (int i = tid; i < cnt; i += 256) {
    unsigned p = gbuf[(size_t)b * BCAP + i];
    lin[i] = p;
    atomicAdd(&lhist[(p >> 16) & 255], 1);
  }
  __syncthreads();
  int v = lhist[tid];
  tmp[tid] = v;
  __syncthreads();
  for (int off = 1; off < 256; off <<= 1) {
    int t = (tid >= off) ? tmp[tid - off] : 0;
    __syncthreads();
    tmp[tid] += t;
    __syncthreads();
  }
  lcur2[tid] = tmp[tid] - v;
  int node = b * 256 + tid;
  if (node < NN) rp[node] = base + tmp[tid] - v;
  __syncthreads();
  for (int i = tid; i < cnt; i += 256) {
    unsigned p = lin[i];
    int pos = atomicAdd(&lcur2[(p >> 16) & 255], 1);
    lsorted[pos] = p & 0xFFFFFFu;
  }
  __syncthreads();
  for (int i = tid; i < cnt; i += 256) spk[base + i] = lsorted[i];
}

// ============ W transposes to fp16 (x is consumed f32 directly by gemm1 now) ============
__global__ void wcast(const float* __restrict__ W1, const float* __restrict__ W2,
                      const float* __restrict__ W3, _Float16* __restrict__ WT1,
                      _Float16* __restrict__ WT2, _Float16* __restrict__ WT3) {
  int i = blockIdx.x * 256 + threadIdx.x;
  if (i < 16384)             { int k = i >> 7, c = i & 127; WT1[c * 128 + k] = (_Float16)W1[i]; }
  else if (i < 32768)        { int j = i - 16384; int k = j >> 7, c = j & 127; WT2[c * 128 + k] = (_Float16)W2[j]; }
  else if (i < 32768 + 4096) { int j = i - 32768; int k = j >> 5, c = j & 31;  WT3[c * 128 + k] = (_Float16)W3[j]; }
}

// ============ MFMA GEMM (K=128): fused attn coefs. CN=128 -> QUARTER-MAJOR out ============
// F32IN: stage f32 X directly (layer 1), else fp16. Quarter q = head q = wave id.
template <int CN, bool F32IN>
__global__ void __launch_bounds__(256)
gemm_mfma(const void* __restrict__ Xv, const _Float16* __restrict__ WT,
          const float* __restrict__ aS, const float* __restrict__ aD,
          _Float16* __restrict__ Hout, float* __restrict__ alS, float* __restrict__ alD) {
  __shared__ _Float16 xt[16 * 64 * 8];
  __shared__ _Float16 wt[16 * CN * 8];
  const int tid = threadIdx.x;
  const int row0 = blockIdx.x * 64;
  {
    int r = tid >> 2, qq = tid & 3;
    int gr = row0 + r;
#pragma unroll
    for (int s = 0; s < 4; ++s) {
      h8 v = {};
      if (gr < NN) {
        if constexpr (F32IN) {
          const float* src = (const float*)Xv + (size_t)gr * 128 + qq * 32 + s * 8;
          float4 a = *(const float4*)src;
          float4 b = *(const float4*)(src + 4);
          v = h8{(_Float16)a.x, (_Float16)a.y, (_Float16)a.z, (_Float16)a.w,
                 (_Float16)b.x, (_Float16)b.y, (_Float16)b.z, (_Float16)b.w};
        } else {
          v = *(const h8*)((const _Float16*)Xv + (size_t)gr * 128 + qq * 32 + s * 8);
        }
      }
      *(h8*)&xt[((qq * 4 + s) * 64 + r) * 8] = v;
    }
  }
  if constexpr (CN == 128) {
    int col = tid >> 1, q = tid & 1;
#pragma unroll
    for (int s = 0; s < 8; ++s) {
      int kc = q * 8 + s;
      *(h8*)&wt[(kc * CN + col) * 8] = *(const h8*)(WT + col * 128 + q * 64 + s * 8);
    }
  } else {
    int col = tid >> 3, q = tid & 7;
#pragma unroll
    for (int s = 0; s < 2; ++s) {
      int kc = q * 2 + s;
      *(h8*)&wt[(kc * CN + col) * 8] = *(const h8*)(WT + col * 128 + q * 16 + s * 8);
    }
  }
  __syncthreads();
  const int w = tid >> 6, ln = tid & 15, lg = (tid & 63) >> 4;
  if constexpr (CN == 128) {
    f32x4 acc[4][2] = {};
#pragma unroll
    for (int ks = 0; ks < 4; ++ks) {
      int kc = ks * 4 + lg;
      h8 a[4], b[2];
#pragma unroll
      for (int mt = 0; mt < 4; ++mt) a[mt] = *(const h8*)&xt[(kc * 64 + mt * 16 + ln) * 8];
#pragma unroll
      for (int nt = 0; nt < 2; ++nt) b[nt] = *(const h8*)&wt[(kc * CN + w * 32 + nt * 16 + ln) * 8];
#pragma unroll
      for (int mt = 0; mt < 4; ++mt)
#pragma unroll
        for (int nt = 0; nt < 2; ++nt)
          acc[mt][nt] = __builtin_amdgcn_mfma_f32_16x16x32_f16(a[mt], b[nt], acc[mt][nt], 0, 0, 0);
    }
    int c0 = w * 32 + ln, c1 = c0 + 16;
    float as0 = aS[c0], as1 = aS[c1], ad0 = aD[c0], ad1 = aD[c1];
#pragma unroll
    for (int mt = 0; mt < 4; ++mt) {
#pragma unroll
      for (int i = 0; i < 4; ++i) {
        int row = row0 + mt * 16 + lg * 4 + i;
        float d0 = acc[mt][0][i], d1 = acc[mt][1][i];
        float ps = d0 * as0 + d1 * as1;
        float pd = d0 * ad0 + d1 * ad1;
        ps += __shfl_xor(ps, 1, 64); pd += __shfl_xor(pd, 1, 64);
        ps += __shfl_xor(ps, 2, 64); pd += __shfl_xor(pd, 2, 64);
        ps += __shfl_xor(ps, 4, 64); pd += __shfl_xor(pd, 4, 64);
        ps += __shfl_xor(ps, 8, 64); pd += __shfl_xor(pd, 8, 64);
        if (row < NN) {
          _Float16* dst = Hout + ((size_t)w * NN + row) * 32;   // quarter-major
          dst[ln]      = (_Float16)d0;
          dst[ln + 16] = (_Float16)d1;
          if (ln == 0) { alS[row * 4 + w] = ps; alD[row * 4 + w] = pd; }
        }
      }
    }
  } else {
    f32x4 acc[2] = {};
#pragma unroll
    for (int ks = 0; ks < 4; ++ks) {
      int kc = ks * 4 + lg;
      h8 a = *(const h8*)&xt[(kc * 64 + w * 16 + ln) * 8];
#pragma unroll
      for (int nt = 0; nt < 2; ++nt) {
        h8 b = *(const h8*)&wt[(kc * CN + nt * 16 + ln) * 8];
        acc[nt] = __builtin_amdgcn_mfma_f32_16x16x32_f16(a, b, acc[nt], 0, 0, 0);
      }
    }
    int c0 = ln, c1 = ln + 16;
    float as0 = aS[c0], as1 = aS[c1], ad0 = aD[c0], ad1 = aD[c1];
#pragma unroll
    for (int i = 0; i < 4; ++i) {
      int row = row0 + w * 16 + lg * 4 + i;
      float d0 = acc[0][i], d1 = acc[1][i];
      float ps = d0 * as0 + d1 * as1;
      float pd = d0 * ad0 + d1 * ad1;
      ps += __shfl_xor(ps, 1, 64); pd += __shfl_xor(pd, 1, 64);
      ps += __shfl_xor(ps, 2, 64); pd += __shfl_xor(pd, 2, 64);
      ps += __shfl_xor(ps, 4, 64); pd += __shfl_xor(pd, 4, 64);
      ps += __shfl_xor(ps, 8, 64); pd += __shfl_xor(pd, 8, 64);
      if (row < NN) {
        Hout[(size_t)row * 32 + c0] = (_Float16)d0;
        Hout[(size_t)row * 32 + c1] = (_Float16)d1;
        if (ln == 0) { alS[row] = ps; alD[row] = pd; }
      }
    }
  }
}

// ============ per-edge attention numerators (4 heads), fp16 planes [4][NE] ============
__global__ void evk(const unsigned* __restrict__ spk, const int* __restrict__ gcur,
                    const int* __restrict__ bbase, const float* __restrict__ alS,
                    const float* __restrict__ alD, unsigned short* __restrict__ evq) {
  int b = blockIdx.x;
  int cnt = min(gcur[b], BCAP), base = bbase[b];
  for (int i = threadIdx.x; i < cnt; i += 256) {
    unsigned p = spk[base + i];
    int s = p & 0xFFFF, d = b * 256 + (int)(p >> 16);
    float4 a4 = ((const float4*)alS)[s];
    float4 d4 = ((const float4*)alD)[d];
    float x0 = a4.x + d4.x; x0 = x0 > 0.f ? x0 : SLOPE * x0;
    float x1 = a4.y + d4.y; x1 = x1 > 0.f ? x1 : SLOPE * x1;
    float x2 = a4.z + d4.z; x2 = x2 > 0.f ? x2 : SLOPE * x2;
    float x3 = a4.w + d4.w; x3 = x3 > 0.f ? x3 : SLOPE * x3;
    evq[(size_t)0 * NE + base + i] = __half_as_ushort(__float2half(__expf(x0)));
    evq[(size_t)1 * NE + base + i] = __half_as_ushort(__float2half(__expf(x1)));
    evq[(size_t)2 * NE + base + i] = __half_as_ushort(__float2half(__expf(x2)));
    evq[(size_t)3 * NE + base + i] = __half_as_ushort(__float2half(__expf(x3)));
  }
}

// ===== quarter-split agg v3: XCD-pinned quarter-major table, instruction parity with r11 =====
// Block = 256 thr = 4 waves; handles 16 nodes x quarter q. Wave: 4 nodes sequential,
// 64 lanes = 4 edge-slots x 16 half2 channels. Per 16-edge chunk per lane: 4 packed shfl +
// 4 x 64B L2-resident gathers + 8 FMA (per-edge parity with r11 across the 4 quarter blocks).
constexpr int NGRP = NN / 16;                    // 3125
constexpr int QGRID = 8 * ((NGRP + 1) / 2);      // 12504

__global__ void gat_agg_h4(const int* __restrict__ rp, const unsigned* __restrict__ spk,
                           const __half2* __restrict__ Hq0, const unsigned short* __restrict__ evq,
                           const float* __restrict__ alS, const float* __restrict__ alD,
                           const float* __restrict__ bias, __half2* __restrict__ outf) {
  const int bid = blockIdx.x;
  const int q  = (bid & 7) >> 1;                 // quarter pinned to XCD pair {2q,2q+1}
  const int ng = (bid >> 3) * 2 + (bid & 1);
  if (ng >= NGRP) return;
  const int w = threadIdx.x >> 6, lane = threadIdx.x & 63;
  const int e4 = lane >> 4, l = lane & 15;
  const __half2* Hq = Hq0 + (size_t)q * NN * 16;          // contiguous 3.2 MB quarter table
  const unsigned short* evp = evq + (size_t)q * NE;
  const float bx = bias[q * 32 + 2 * l], by = bias[q * 32 + 2 * l + 1];
#pragma unroll
  for (int n = 0; n < 4; ++n) {
    const int node = ng * 16 + w * 4 + n;
    int beg = rp[node], end = rp[node + 1];
    float accx = 0.f, accy = 0.f, sm = 0.f;
    for (int ch = beg; ch < end; ch += 16) {
      unsigned pk = (unsigned)node;              // ev bits = 0 -> alpha 0, safe gather idx
      if (lane < 16 && ch + lane < end) {
        unsigned sv = spk[ch + lane] & 0xFFFFu;
        unsigned evb = (unsigned)evp[ch + lane];
        sm += __half2float(__ushort_as_half((unsigned short)evb));
        pk = (evb << 16) | sv;
      }
      unsigned p0 = __shfl(pk, e4 * 4 + 0, 64);
      unsigned p1 = __shfl(pk, e4 * 4 + 1, 64);
      unsigned p2 = __shfl(pk, e4 * 4 + 2, 64);
      unsigned p3 = __shfl(pk, e4 * 4 + 3, 64);
      __half2 h0 = Hq[(size_t)(p0 & 0xFFFFu) * 16 + l];
      __half2 h1 = Hq[(size_t)(p1 & 0xFFFFu) * 16 + l];
      __half2 h2 = Hq[(size_t)(p2 & 0xFFFFu) * 16 + l];
      __half2 h3 = Hq[(size_t)(p3 & 0xFFFFu) * 16 + l];
      float a0 = __half2float(__ushort_as_half((unsigned short)(p0 >> 16)));
      float a1 = __half2float(__ushort_as_half((unsigned short)(p1 >> 16)));
      float a2 = __half2float(__ushort_as_half((unsigned short)(p2 >> 16)));
      float a3 = __half2float(__ushort_as_half((unsigned short)(p3 >> 16)));
      float2 f0 = __half22float2(h0), f1 = __half22float2(h1);
      float2 f2 = __half22float2(h2), f3 = __half22float2(h3);
      accx = fmaf(f0.x, a0, accx); accy = fmaf(f0.y, a0, accy);
      accx = fmaf(f1.x, a1, accx); accy = fmaf(f1.y, a1, accy);
      accx = fmaf(f2.x, a2, accx); accy = fmaf(f2.y, a2, accy);
      accx = fmaf(f3.x, a3, accx); accy = fmaf(f3.y, a3, accy);
    }
    // cross-slot reduce (channels repeat across the 4 edge-slot groups)
    accx += __shfl_xor(accx, 16, 64); accx += __shfl_xor(accx, 32, 64);
    accy += __shfl_xor(accy, 16, 64); accy += __shfl_xor(accy, 32, 64);
#pragma unroll
    for (int off = 1; off <= 32; off <<= 1) sm += __shfl_xor(sm, off, 64);  // lanes>=16 carry 0
    // self-loop analytic
    float xs = alS[node * 4 + q] + alD[node * 4 + q];
    xs = xs > 0.f ? xs : SLOPE * xs;
    float evs = __expf(xs);
    float2 fs = __half22float2(Hq[(size_t)node * 16 + l]);
    accx += fs.x * evs;
    accy += fs.y * evs;
    sm += evs;
    float inv = 1.0f / sm;
    float vx = accx * inv + bx;
    float vy = accy * inv + by;
    vx = vx > 0.f ? vx : expm1f(vx);
    vy = vy > 0.f ? vy : expm1f(vy);
    if (lane < 16) outf[(size_t)node * 64 + q * 16 + l] = __floats2half2_rn(vx, vy);
  }
}

// ===== fused softmax+agg H=1 (F=32): 16 lanes/node, packed single shfl (r11) =====
__global__ void gat_agg_h1(const int* __restrict__ rp, const unsigned* __restrict__ spk,
                           const __half2* __restrict__ Hf2, const float* __restrict__ alS,
                           const float* __restrict__ alD, const float* __restrict__ bias,
                           __half2* __restrict__ outf) {
  int node = (blockIdx.x * 256 + threadIdx.x) >> 4;
  int lane = threadIdx.x & 15;
  if (node >= NN) return;
  int beg = rp[node], end = rp[node + 1];
  float ad = alD[node];
  float xsf = alS[node] + ad;
  xsf = xsf > 0.f ? xsf : SLOPE * xsf;
  float evs = __expf(xsf);
  __half2 hself = Hf2[(size_t)node * 16 + lane];
  float accx = __low2float(hself) * evs;
  float accy = __high2float(hself) * evs;
  float sm = (lane == 0) ? evs : 0.f;
  for (int ch = beg; ch < end; ch += 16) {
    int cnt = end - ch;
    unsigned pk = (unsigned)node;
    if (lane < cnt) {
      int sv = (int)(spk[ch + lane] & 0xFFFFu);
      float x = alS[sv] + ad;
      x = x > 0.f ? x : SLOPE * x;
      float ev = __expf(x);
      sm += ev;
      unsigned evb = (unsigned)__half_as_ushort(__float2half(ev));
      pk = (evb << 16) | (unsigned)sv;
    }
    unsigned parr[16];
#pragma unroll
    for (int e = 0; e < 16; ++e) parr[e] = __shfl(pk, e, 16);
    __half2 hv[16];
#pragma unroll
    for (int e = 0; e < 16; ++e)
      hv[e] = Hf2[(size_t)(parr[e] & 0xFFFFu) * 16 + lane];
#pragma unroll
    for (int e = 0; e < 16; ++e) {
      float a = __half2float(__ushort_as_half((unsigned short)(parr[e] >> 16)));
      float2 f = __half22float2(hv[e]);
      accx = fmaf(f.x, a, accx);
      accy = fmaf(f.y, a, accy);
    }
  }
#pragma unroll
  for (int off = 8; off >= 1; off >>= 1) sm += __shfl_xor(sm, off, 16);
  float inv = 1.0f / sm;
  float vx = accx * inv + bias[2 * lane];
  float vy = accy * inv + bias[2 * lane + 1];
  vx = vx > 0.f ? vx : expm1f(vx);
  vy = vy > 0.f ? vy : expm1f(vy);
  outf[(size_t)node * 16 + lane] = __floats2half2_rn(vx, vy);
}

// ======================= fused pool (sorted batch) + mu/logvar heads =======================
__device__ __forceinline__ int lb_batch(const int* __restrict__ b, int val) {
  int lo = 0, hi = NN;
  while (lo < hi) { int mid = (lo + hi) >> 1; if (b[mid] < val) lo = mid + 1; else hi = mid; }
  return lo;
}

__global__ void pool_head(const __half2* __restrict__ feat, const int* __restrict__ batch,
                          const float* __restrict__ Wmu, const float* __restrict__ bmu,
                          const float* __restrict__ Wlv, const float* __restrict__ blv,
                          float* __restrict__ out) {
  int g = blockIdx.x;
  int start = lb_batch(batch, g), end = lb_batch(batch, g + 1);
  int cp = threadIdx.x & 15, sub = threadIdx.x >> 4;
  float ax = 0.f, ay = 0.f;
  for (int n = start + sub; n < end; n += 16) {
    __half2 v = feat[(size_t)n * 16 + cp];
    ax += __low2float(v);
    ay += __high2float(v);
  }
  __shared__ float red[16][32];
  __shared__ float pl[32];
  red[sub][2 * cp] = ax;
  red[sub][2 * cp + 1] = ay;
  __syncthreads();
  if (threadIdx.x < 32) {
    float s = 0.f;
#pragma unroll
    for (int i = 0; i < 16; ++i) s += red[i][threadIdx.x];
    pl[threadIdx.x] = s / fmaxf((float)(end - start), 1.0f);
  }
  __syncthreads();
  if (threadIdx.x < NLAT) {
    int l = threadIdx.x;
    float mu = bmu[l], lv = blv[l];
#pragma unroll
    for (int k = 0; k < 32; ++k) {
      float p = pl[k];
      mu = fmaf(p, Wmu[k * NLAT + l], mu);
      lv = fmaf(p, Wlv[k * NLAT + l], lv);
    }
    out[g * NLAT + l] = mu;
    out[NG * NLAT + g * NLAT + l] = lv;
  }
}

extern "C" void kernel_launch(void* const* d_in, const int* in_sizes, int n_in,
                              void* d_out, int out_size, void* d_ws, size_t ws_size,
                              hipStream_t stream) {
  const float* x     = (const float*)d_in[0];
  const float* W1    = (const float*)d_in[1];
  const float* as1   = (const float*)d_in[2];
  const float* ad1   = (const float*)d_in[3];
  const float* b1    = (const float*)d_in[4];
  const float* W2    = (const float*)d_in[5];
  const float* as2   = (const float*)d_in[6];
  const float* ad2   = (const float*)d_in[7];
  const float* b2    = (const float*)d_in[8];
  const float* W3    = (const float*)d_in[9];
  const float* as3   = (const float*)d_in[10];
  const float* ad3   = (const float*)d_in[11];
  const float* b3    = (const float*)d_in[12];
  const float* Wmu   = (const float*)d_in[13];
  const float* bmu   = (const float*)d_in[14];
  const float* Wlv   = (const float*)d_in[15];
  const float* blv   = (const float*)d_in[16];
  const int*   ei    = (const int*)d_in[17];
  const int*   batch = (const int*)d_in[18];
  float* out = (float*)d_out;

  _Float16* A   = (_Float16*)d_ws;                  // [4][N][32] fp16 quarter-major h
  _Float16* Bh  = A + (size_t)NN * 128;             // [N,128] fp16 features (agg out / gemm in)
  float* alS    = (float*)(Bh + (size_t)NN * 128);  // [N,4]
  float* alD    = alS + (size_t)NN * 4;             // [N,4]
  _Float16* WT1 = (_Float16*)(alD + (size_t)NN * 4);// [128*128]
  _Float16* WT2 = WT1 + 16384;                      // [128*128]
  _Float16* WT3 = WT2 + 16384;                      // [32*128]
  unsigned short* evq = (unsigned short*)(WT3 + 4096);  // [4][NE] fp16 ev planes
  int* rp       = (int*)(evq + (size_t)4 * NE);     // [N+1]
  int* gcur     = rp + NN + 1;                      // [256]
  int* bbase    = gcur + 256;                       // [256]
  unsigned* gbuf = (unsigned*)(bbase + 256);        // [NBK*BCAP]
  unsigned* spk  = gbuf + (size_t)NBK * BCAP;       // [NE] packed (dlocal<<16|src)

  dim3 blk(256);

  // ---------------- CSR build + weight prep ----------------
  hipMemsetAsync(gcur, 0, 256 * sizeof(int), stream);
  p1_bucket<<<NB1, blk, 0, stream>>>(ei, gcur, gbuf);
  p2_sort<<<NBK, blk, 0, stream>>>(gbuf, gcur, bbase, rp, spk);
  wcast<<<144, blk, 0, stream>>>(W1, W2, W3, WT1, WT2, WT3);

  const int GB = (NN + 63) / 64;
  // ---------------- layer 1 (f32 x input, no xcast) ----------------
  gemm_mfma<128, true><<<GB, blk, 0, stream>>>(x, WT1, as1, ad1, A, alS, alD);
  evk<<<NBK, blk, 0, stream>>>(spk, gcur, bbase, alS, alD, evq);
  gat_agg_h4<<<QGRID, blk, 0, stream>>>(rp, spk, (const __half2*)A, evq, alS, alD, b1, (__half2*)Bh);
  // ---------------- layer 2 ----------------
  gemm_mfma<128, false><<<GB, blk, 0, stream>>>(Bh, WT2, as2, ad2, A, alS, alD);
  evk<<<NBK, blk, 0, stream>>>(spk, gcur, bbase, alS, alD, evq);
  gat_agg_h4<<<QGRID, blk, 0, stream>>>(rp, spk, (const __half2*)A, evq, alS, alD, b2, (__half2*)Bh);
  // ---------------- layer 3 ----------------
  gemm_mfma<32, false><<<GB, blk, 0, stream>>>(Bh, WT3, as3, ad3, A, alS, alD);
  gat_agg_h1<<<(NN * 16) / 256, blk, 0, stream>>>(rp, spk, (const __half2*)A, alS, alD, b3, (__half2*)Bh);

  // ---------------- fused pool + heads ----------------
  pool_head<<<NG, blk, 0, stream>>>((const __half2*)Bh, batch, Wmu, bmu, Wlv, blv, out);
}

// Round 13
// 194.007 us; speedup vs baseline: 1.4082x; 1.4082x over previous
//
#include <hip/hip_runtime.h>
#include <hip/hip_fp16.h>

constexpr int NN   = 50000;            // nodes
constexpr int NE   = 800000;           // edges (self-loops handled analytically)
constexpr int NG   = 512;              // graphs
constexpr int NLAT = 64;               // latent dim
constexpr float SLOPE = 0.2f;          // leaky relu slope

constexpr int NBK  = 196;              // coarse buckets of 256 nodes
constexpr int BCAP = 8192;             // per-bucket capacity
constexpr int EPB  = 4096;             // edges per pass-1 block
constexpr int NB1  = (NE + EPB - 1) / EPB;   // 196

typedef _Float16 h8 __attribute__((ext_vector_type(8)));
typedef float f32x4 __attribute__((ext_vector_type(4)));

// ============ pass 1: bucket edges by dst>>8 with LDS staging ============
__global__ void p1_bucket(const int* __restrict__ ei, int* __restrict__ gcur,
                          unsigned* __restrict__ gbuf) {
  __shared__ unsigned lin[EPB];
  __shared__ unsigned lout[EPB];
  __shared__ int lhist[NBK], lbase[NBK + 1], lcur[NBK], goff[NBK];
  __shared__ int tmp[256];
  const int tid = threadIdx.x;
  if (tid < NBK) lhist[tid] = 0;
  __syncthreads();
  const int e0 = blockIdx.x * EPB;
#pragma unroll
  for (int i = 0; i < EPB / 256; ++i) {
    int e = e0 + i * 256 + tid;
    unsigned p = 0xFFFFFFFFu;
    if (e < NE) {
      int s = ei[e], d = ei[NE + e];
      p = ((unsigned)(d >> 8) << 24) | ((unsigned)(d & 255) << 16) | (unsigned)s;
      atomicAdd(&lhist[d >> 8], 1);
    }
    lin[i * 256 + tid] = p;
  }
  __syncthreads();
  int v = (tid < NBK) ? lhist[tid] : 0;
  tmp[tid] = v;
  __syncthreads();
  for (int off = 1; off < 256; off <<= 1) {
    int t = (tid >= off) ? tmp[tid - off] : 0;
    __syncthreads();
    tmp[tid] += t;
    __syncthreads();
  }
  if (tid < NBK) { lbase[tid] = tmp[tid] - v; lcur[tid] = tmp[tid] - v; }
  if (tid == NBK - 1) lbase[NBK] = tmp[NBK - 1];
  __syncthreads();
#pragma unroll
  for (int i = 0; i < EPB / 256; ++i) {
    unsigned p = lin[i * 256 + tid];
    if (p != 0xFFFFFFFFu) {
      int b = p >> 24;
      int pos = atomicAdd(&lcur[b], 1);
      lout[pos] = p & 0xFFFFFFu;
    }
  }
  if (tid < NBK) goff[tid] = atomicAdd(&gcur[tid], lhist[tid]);
  __syncthreads();
  const int total = lbase[NBK];
  for (int i = tid; i < total; i += 256) {
    int lo = 0, hi = NBK - 1;
    while (lo < hi) { int mid = (lo + hi + 1) >> 1; if (lbase[mid] <= i) lo = mid; else hi = mid - 1; }
    gbuf[(size_t)lo * BCAP + goff[lo] + (i - lbase[lo])] = lout[i];
  }
}

// ============ pass 2: fused bucket-base scan + per-bucket counting sort ============
__global__ void p2_sort(const unsigned* __restrict__ gbuf, const int* __restrict__ gcur,
                        int* __restrict__ bbase_out, int* __restrict__ rp,
                        unsigned* __restrict__ spk) {
  __shared__ unsigned lin[BCAP];
  __shared__ unsigned lsorted[BCAP];
  __shared__ int lhist[256], lcur2[256], tmp[256], sscan[256];
  const int tid = threadIdx.x;
  const int b = blockIdx.x;
  int gv = (tid < NBK) ? gcur[tid] : 0;
  tmp[tid] = gv;
  __syncthreads();
  for (int off = 1; off < 256; off <<= 1) {
    int t = (tid >= off) ? tmp[tid - off] : 0;
    __syncthreads();
    tmp[tid] += t;
    __syncthreads();
  }
  sscan[tid] = tmp[tid];
  __syncthreads();
  const int base = b ? sscan[b - 1] : 0;
  const int cnt = min(gcur[b], BCAP);
  if (tid == 0) { bbase_out[b] = base; if (b == 0) rp[NN] = NE; }
  lhist[tid] = 0;
  __syncthreads();
  for (int i = tid; i < cnt; i += 256) {
    unsigned p = gbuf[(size_t)b * BCAP + i];
    lin[i] = p;
    atomicAdd(&lhist[(p >> 16) & 255], 1);
  }
  __syncthreads();
  int v = lhist[tid];
  tmp[tid] = v;
  __syncthreads();
  for (int off = 1; off < 256; off <<= 1) {
    int t = (tid >= off) ? tmp[tid - off] : 0;
    __syncthreads();
    tmp[tid] += t;
    __syncthreads();
  }
  lcur2[tid] = tmp[tid] - v;
  int node = b * 256 + tid;
  if (node < NN) rp[node] = base + tmp[tid] - v;
  __syncthreads();
  for (int i = tid; i < cnt; i += 256) {
    unsigned p = lin[i];
    int pos = atomicAdd(&lcur2[(p >> 16) & 255], 1);
    lsorted[pos] = p & 0xFFFFFFu;
  }
  __syncthreads();
  for (int i = tid; i < cnt; i += 256) spk[base + i] = lsorted[i];
}

// ============ W transposes to fp16 (x consumed f32 directly by layer-1 GEMM) ============
__global__ void wcast(const float* __restrict__ W1, const float* __restrict__ W2,
                      const float* __restrict__ W3, _Float16* __restrict__ WT1,
                      _Float16* __restrict__ WT2, _Float16* __restrict__ WT3) {
  int i = blockIdx.x * 256 + threadIdx.x;
  if (i < 16384)             { int k = i >> 7, c = i & 127; WT1[c * 128 + k] = (_Float16)W1[i]; }
  else if (i < 32768)        { int j = i - 16384; int k = j >> 7, c = j & 127; WT2[c * 128 + k] = (_Float16)W2[j]; }
  else if (i < 32768 + 4096) { int j = i - 32768; int k = j >> 5, c = j & 31;  WT3[c * 128 + k] = (_Float16)W3[j]; }
}

// ============ MFMA GEMM (K=128): fp16 compute, f32 accum; fused attn coefs; FLAT output ============
// F32IN: stage f32 X with inline cast (layer 1); else fp16 input.
template <int CN, bool F32IN>   // CN = 128 (H=4) or 32 (H=1)
__global__ void __launch_bounds__(256)
gemm_mfma(const void* __restrict__ Xv, const _Float16* __restrict__ WT,
          const float* __restrict__ aS, const float* __restrict__ aD,
          _Float16* __restrict__ Hout, float* __restrict__ alS, float* __restrict__ alD) {
  __shared__ _Float16 xt[16 * 64 * 8];
  __shared__ _Float16 wt[16 * CN * 8];
  const int tid = threadIdx.x;
  const int row0 = blockIdx.x * 64;
  {
    int r = tid >> 2, qq = tid & 3;
    int gr = row0 + r;
#pragma unroll
    for (int s = 0; s < 4; ++s) {
      h8 v = {};
      if (gr < NN) {
        if constexpr (F32IN) {
          const float* src = (const float*)Xv + (size_t)gr * 128 + qq * 32 + s * 8;
          float4 a = *(const float4*)src;
          float4 b = *(const float4*)(src + 4);
          v = h8{(_Float16)a.x, (_Float16)a.y, (_Float16)a.z, (_Float16)a.w,
                 (_Float16)b.x, (_Float16)b.y, (_Float16)b.z, (_Float16)b.w};
        } else {
          v = *(const h8*)((const _Float16*)Xv + (size_t)gr * 128 + qq * 32 + s * 8);
        }
      }
      *(h8*)&xt[((qq * 4 + s) * 64 + r) * 8] = v;
    }
  }
  if constexpr (CN == 128) {
    int col = tid >> 1, q = tid & 1;
#pragma unroll
    for (int s = 0; s < 8; ++s) {
      int kc = q * 8 + s;
      *(h8*)&wt[(kc * CN + col) * 8] = *(const h8*)(WT + col * 128 + q * 64 + s * 8);
    }
  } else {
    int col = tid >> 3, q = tid & 7;
#pragma unroll
    for (int s = 0; s < 2; ++s) {
      int kc = q * 2 + s;
      *(h8*)&wt[(kc * CN + col) * 8] = *(const h8*)(WT + col * 128 + q * 16 + s * 8);
    }
  }
  __syncthreads();
  const int w = tid >> 6, ln = tid & 15, lg = (tid & 63) >> 4;
  if constexpr (CN == 128) {
    f32x4 acc[4][2] = {};
#pragma unroll
    for (int ks = 0; ks < 4; ++ks) {
      int kc = ks * 4 + lg;
      h8 a[4], b[2];
#pragma unroll
      for (int mt = 0; mt < 4; ++mt) a[mt] = *(const h8*)&xt[(kc * 64 + mt * 16 + ln) * 8];
#pragma unroll
      for (int nt = 0; nt < 2; ++nt) b[nt] = *(const h8*)&wt[(kc * CN + w * 32 + nt * 16 + ln) * 8];
#pragma unroll
      for (int mt = 0; mt < 4; ++mt)
#pragma unroll
        for (int nt = 0; nt < 2; ++nt)
          acc[mt][nt] = __builtin_amdgcn_mfma_f32_16x16x32_f16(a[mt], b[nt], acc[mt][nt], 0, 0, 0);
    }
    int c0 = w * 32 + ln, c1 = c0 + 16;
    float as0 = aS[c0], as1 = aS[c1], ad0 = aD[c0], ad1 = aD[c1];
#pragma unroll
    for (int mt = 0; mt < 4; ++mt) {
#pragma unroll
      for (int i = 0; i < 4; ++i) {
        int row = row0 + mt * 16 + lg * 4 + i;
        float d0 = acc[mt][0][i], d1 = acc[mt][1][i];
        float ps = d0 * as0 + d1 * as1;
        float pd = d0 * ad0 + d1 * ad1;
        ps += __shfl_xor(ps, 1, 64); pd += __shfl_xor(pd, 1, 64);
        ps += __shfl_xor(ps, 2, 64); pd += __shfl_xor(pd, 2, 64);
        ps += __shfl_xor(ps, 4, 64); pd += __shfl_xor(pd, 4, 64);
        ps += __shfl_xor(ps, 8, 64); pd += __shfl_xor(pd, 8, 64);
        if (row < NN) {
          Hout[(size_t)row * 128 + c0] = (_Float16)d0;
          Hout[(size_t)row * 128 + c1] = (_Float16)d1;
          if (ln == 0) { alS[row * 4 + w] = ps; alD[row * 4 + w] = pd; }
        }
      }
    }
  } else {
    f32x4 acc[2] = {};
#pragma unroll
    for (int ks = 0; ks < 4; ++ks) {
      int kc = ks * 4 + lg;
      h8 a = *(const h8*)&xt[(kc * 64 + w * 16 + ln) * 8];
#pragma unroll
      for (int nt = 0; nt < 2; ++nt) {
        h8 b = *(const h8*)&wt[(kc * CN + nt * 16 + ln) * 8];
        acc[nt] = __builtin_amdgcn_mfma_f32_16x16x32_f16(a, b, acc[nt], 0, 0, 0);
      }
    }
    int c0 = ln, c1 = ln + 16;
    float as0 = aS[c0], as1 = aS[c1], ad0 = aD[c0], ad1 = aD[c1];
#pragma unroll
    for (int i = 0; i < 4; ++i) {
      int row = row0 + w * 16 + lg * 4 + i;
      float d0 = acc[0][i], d1 = acc[1][i];
      float ps = d0 * as0 + d1 * as1;
      float pd = d0 * ad0 + d1 * ad1;
      ps += __shfl_xor(ps, 1, 64); pd += __shfl_xor(pd, 1, 64);
      ps += __shfl_xor(ps, 2, 64); pd += __shfl_xor(pd, 2, 64);
      ps += __shfl_xor(ps, 4, 64); pd += __shfl_xor(pd, 4, 64);
      ps += __shfl_xor(ps, 8, 64); pd += __shfl_xor(pd, 8, 64);
      if (row < NN) {
        Hout[(size_t)row * 32 + c0] = (_Float16)d0;
        Hout[(size_t)row * 32 + c1] = (_Float16)d1;
        if (ln == 0) { alS[row] = ps; alD[row] = pd; }
      }
    }
  }
}

// ===== fused softmax+agg H=4 (r11, best measured): one wave/node, packed (ev|src) shfl =====
// lane covers channel pair (2*lane, 2*lane+1); its head = lane>>4 = stats-lane head hh.
// Packed word: fp16(ev) high 16 bits, src (<65536) low 16 -> ONE ds_bpermute per edge.
// No max-subtraction: logits O(+-6) at this data scale; exp() safe in f32 and fp16.
__global__ void gat_agg_h4(const int* __restrict__ rp, const unsigned* __restrict__ spk,
                           const __half2* __restrict__ Hf2, const float* __restrict__ alS,
                           const float* __restrict__ alD, const float* __restrict__ bias,
                           __half2* __restrict__ outf) {
  int node = (blockIdx.x * 256 + threadIdx.x) >> 6;
  int lane = threadIdx.x & 63;
  if (node >= NN) return;
  int beg = rp[node], end = rp[node + 1];
  int el = lane & 15, hh = lane >> 4;
  const int hb = lane & 48;                     // head-group base for shfl
  float ad_h = alD[node * 4 + hh];
  float xsf = alS[node * 4 + hh] + ad_h;        // self-loop analytic
  xsf = xsf > 0.f ? xsf : SLOPE * xsf;
  float evs = __expf(xsf);
  __half2 hself = Hf2[(size_t)node * 64 + lane];
  float accx = __low2float(hself) * evs;
  float accy = __high2float(hself) * evs;
  float sm = (el == 0) ? evs : 0.f;
  for (int ch = beg; ch < end; ch += 16) {
    int cnt = end - ch;
    unsigned pk = (unsigned)node;               // ev bits = 0 -> alpha 0, safe gather idx
    if (el < cnt) {
      int sv = (int)(spk[ch + el] & 0xFFFFu);
      float x = alS[sv * 4 + hh] + ad_h;
      x = x > 0.f ? x : SLOPE * x;
      float ev = __expf(x);
      sm += ev;
      unsigned evb = (unsigned)__half_as_ushort(__float2half(ev));
      pk = (evb << 16) | (unsigned)sv;
    }
    unsigned parr[16];
#pragma unroll
    for (int e = 0; e < 16; ++e) parr[e] = __shfl(pk, hb + e, 64);  // 1 shfl/edge
    __half2 hv[16];
#pragma unroll
    for (int e = 0; e < 16; ++e)                // 16 row gathers in flight
      hv[e] = Hf2[(size_t)(parr[e] & 0xFFFFu) * 64 + lane];
#pragma unroll
    for (int e = 0; e < 16; ++e) {
      float a = __half2float(__ushort_as_half((unsigned short)(parr[e] >> 16)));
      float2 f = __half22float2(hv[e]);
      accx = fmaf(f.x, a, accx);
      accy = fmaf(f.y, a, accy);
    }
  }
#pragma unroll
  for (int off = 8; off >= 1; off >>= 1) sm += __shfl_xor(sm, off, 64);  // per-head denom
  float inv = 1.0f / sm;
  float vx = accx * inv + bias[2 * lane];
  float vy = accy * inv + bias[2 * lane + 1];
  vx = vx > 0.f ? vx : expm1f(vx);
  vy = vy > 0.f ? vy : expm1f(vy);
  outf[(size_t)node * 64 + lane] = __floats2half2_rn(vx, vy);
}

// ===== fused softmax+agg H=1 (F=32): 16 lanes/node, packed single shfl =====
__global__ void gat_agg_h1(const int* __restrict__ rp, const unsigned* __restrict__ spk,
                           const __half2* __restrict__ Hf2, const float* __restrict__ alS,
                           const float* __restrict__ alD, const float* __restrict__ bias,
                           __half2* __restrict__ outf) {
  int node = (blockIdx.x * 256 + threadIdx.x) >> 4;
  int lane = threadIdx.x & 15;
  if (node >= NN) return;
  int beg = rp[node], end = rp[node + 1];
  float ad = alD[node];
  float xsf = alS[node] + ad;
  xsf = xsf > 0.f ? xsf : SLOPE * xsf;
  float evs = __expf(xsf);
  __half2 hself = Hf2[(size_t)node * 16 + lane];
  float accx = __low2float(hself) * evs;
  float accy = __high2float(hself) * evs;
  float sm = (lane == 0) ? evs : 0.f;
  for (int ch = beg; ch < end; ch += 16) {
    int cnt = end - ch;
    unsigned pk = (unsigned)node;
    if (lane < cnt) {
      int sv = (int)(spk[ch + lane] & 0xFFFFu);
      float x = alS[sv] + ad;
      x = x > 0.f ? x : SLOPE * x;
      float ev = __expf(x);
      sm += ev;
      unsigned evb = (unsigned)__half_as_ushort(__float2half(ev));
      pk = (evb << 16) | (unsigned)sv;
    }
    unsigned parr[16];
#pragma unroll
    for (int e = 0; e < 16; ++e) parr[e] = __shfl(pk, e, 16);
    __half2 hv[16];
#pragma unroll
    for (int e = 0; e < 16; ++e)
      hv[e] = Hf2[(size_t)(parr[e] & 0xFFFFu) * 16 + lane];
#pragma unroll
    for (int e = 0; e < 16; ++e) {
      float a = __half2float(__ushort_as_half((unsigned short)(parr[e] >> 16)));
      float2 f = __half22float2(hv[e]);
      accx = fmaf(f.x, a, accx);
      accy = fmaf(f.y, a, accy);
    }
  }
#pragma unroll
  for (int off = 8; off >= 1; off >>= 1) sm += __shfl_xor(sm, off, 16);
  float inv = 1.0f / sm;
  float vx = accx * inv + bias[2 * lane];
  float vy = accy * inv + bias[2 * lane + 1];
  vx = vx > 0.f ? vx : expm1f(vx);
  vy = vy > 0.f ? vy : expm1f(vy);
  outf[(size_t)node * 16 + lane] = __floats2half2_rn(vx, vy);
}

// ======================= fused pool (sorted batch) + mu/logvar heads =======================
__device__ __forceinline__ int lb_batch(const int* __restrict__ b, int val) {
  int lo = 0, hi = NN;
  while (lo < hi) { int mid = (lo + hi) >> 1; if (b[mid] < val) lo = mid + 1; else hi = mid; }
  return lo;
}

__global__ void pool_head(const __half2* __restrict__ feat, const int* __restrict__ batch,
                          const float* __restrict__ Wmu, const float* __restrict__ bmu,
                          const float* __restrict__ Wlv, const float* __restrict__ blv,
                          float* __restrict__ out) {
  int g = blockIdx.x;
  int start = lb_batch(batch, g), end = lb_batch(batch, g + 1);
  int cp = threadIdx.x & 15, sub = threadIdx.x >> 4;
  float ax = 0.f, ay = 0.f;
  for (int n = start + sub; n < end; n += 16) {
    __half2 v = feat[(size_t)n * 16 + cp];
    ax += __low2float(v);
    ay += __high2float(v);
  }
  __shared__ float red[16][32];
  __shared__ float pl[32];
  red[sub][2 * cp] = ax;
  red[sub][2 * cp + 1] = ay;
  __syncthreads();
  if (threadIdx.x < 32) {
    float s = 0.f;
#pragma unroll
    for (int i = 0; i < 16; ++i) s += red[i][threadIdx.x];
    pl[threadIdx.x] = s / fmaxf((float)(end - start), 1.0f);
  }
  __syncthreads();
  if (threadIdx.x < NLAT) {
    int l = threadIdx.x;
    float mu = bmu[l], lv = blv[l];
#pragma unroll
    for (int k = 0; k < 32; ++k) {
      float p = pl[k];
      mu = fmaf(p, Wmu[k * NLAT + l], mu);
      lv = fmaf(p, Wlv[k * NLAT + l], lv);
    }
    out[g * NLAT + l] = mu;
    out[NG * NLAT + g * NLAT + l] = lv;
  }
}

extern "C" void kernel_launch(void* const* d_in, const int* in_sizes, int n_in,
                              void* d_out, int out_size, void* d_ws, size_t ws_size,
                              hipStream_t stream) {
  const float* x     = (const float*)d_in[0];
  const float* W1    = (const float*)d_in[1];
  const float* as1   = (const float*)d_in[2];
  const float* ad1   = (const float*)d_in[3];
  const float* b1    = (const float*)d_in[4];
  const float* W2    = (const float*)d_in[5];
  const float* as2   = (const float*)d_in[6];
  const float* ad2   = (const float*)d_in[7];
  const float* b2    = (const float*)d_in[8];
  const float* W3    = (const float*)d_in[9];
  const float* as3   = (const float*)d_in[10];
  const float* ad3   = (const float*)d_in[11];
  const float* b3    = (const float*)d_in[12];
  const float* Wmu   = (const float*)d_in[13];
  const float* bmu   = (const float*)d_in[14];
  const float* Wlv   = (const float*)d_in[15];
  const float* blv   = (const float*)d_in[16];
  const int*   ei    = (const int*)d_in[17];
  const int*   batch = (const int*)d_in[18];
  float* out = (float*)d_out;

  _Float16* A   = (_Float16*)d_ws;                  // [N,128] fp16 h (gemm out, flat)
  _Float16* Bh  = A + (size_t)NN * 128;             // [N,128] fp16 features
  float* alS    = (float*)(Bh + (size_t)NN * 128);  // [N,4]
  float* alD    = alS + (size_t)NN * 4;             // [N,4]
  _Float16* WT1 = (_Float16*)(alD + (size_t)NN * 4);// [128*128]
  _Float16* WT2 = WT1 + 16384;                      // [128*128]
  _Float16* WT3 = WT2 + 16384;                      // [32*128]
  int* rp       = (int*)(WT3 + 4096);               // [N+1]
  int* gcur     = rp + NN + 1;                      // [256]
  int* bbase    = gcur + 256;                       // [256]
  unsigned* gbuf = (unsigned*)(bbase + 256);        // [NBK*BCAP]
  unsigned* spk  = gbuf + (size_t)NBK * BCAP;       // [NE] packed (dlocal<<16|src)

  dim3 blk(256);

  // ---------------- CSR build + weight prep ----------------
  hipMemsetAsync(gcur, 0, 256 * sizeof(int), stream);
  p1_bucket<<<NB1, blk, 0, stream>>>(ei, gcur, gbuf);
  p2_sort<<<NBK, blk, 0, stream>>>(gbuf, gcur, bbase, rp, spk);
  wcast<<<144, blk, 0, stream>>>(W1, W2, W3, WT1, WT2, WT3);

  const int GB = (NN + 63) / 64;
  // ---------------- layer 1 (f32 x input, no xcast) ----------------
  gemm_mfma<128, true><<<GB, blk, 0, stream>>>(x, WT1, as1, ad1, A, alS, alD);
  gat_agg_h4<<<(NN * 64) / 256, blk, 0, stream>>>(rp, spk, (const __half2*)A, alS, alD, b1, (__half2*)Bh);
  // ---------------- layer 2 ----------------
  gemm_mfma<128, false><<<GB, blk, 0, stream>>>(Bh, WT2, as2, ad2, A, alS, alD);
  gat_agg_h4<<<(NN * 64) / 256, blk, 0, stream>>>(rp, spk, (const __half2*)A, alS, alD, b2, (__half2*)Bh);
  // ---------------- layer 3 ----------------
  gemm_mfma<32, false><<<GB, blk, 0, stream>>>(Bh, WT3, as3, ad3, A, alS, alD);
  gat_agg_h1<<<(NN * 16) / 256, blk, 0, stream>>>(rp, spk, (const __half2*)A, alS, alD, b3, (__half2*)Bh);

  // ---------------- fused pool + heads ----------------
  pool_head<<<NG, blk, 0, stream>>>((const __half2*)Bh, batch, Wmu, bmu, Wlv, blv, out);
}

// Round 14
// 192.161 us; speedup vs baseline: 1.4217x; 1.0096x over previous
//
#include <hip/hip_runtime.h>
#include <hip/hip_fp16.h>

constexpr int NN   = 50000;            // nodes
constexpr int NE   = 800000;           // edges (self-loops handled analytically)
constexpr int NG   = 512;              // graphs
constexpr int NLAT = 64;               // latent dim
constexpr float SLOPE = 0.2f;          // leaky relu slope

constexpr int NBK  = 196;              // coarse buckets of 256 nodes
constexpr int BCAP = 8192;             // per-bucket capacity
constexpr int EPB  = 4096;             // edges per pass-1 block
constexpr int NB1  = (NE + EPB - 1) / EPB;   // 196

typedef _Float16 h8 __attribute__((ext_vector_type(8)));
typedef float f32x4 __attribute__((ext_vector_type(4)));
struct __align__(8) h2x2 { __half2 a, b; };   // 8B: forces dwordx2 loads

// ============ pass 1: bucket edges by dst>>8; direct-bucket copy-out (no binary search) ============
__global__ void p1_bucket(const int* __restrict__ ei, int* __restrict__ gcur,
                          unsigned* __restrict__ gbuf) {
  __shared__ unsigned lin[EPB];
  __shared__ unsigned lout[EPB];
  __shared__ int lhist[NBK], lbase[NBK + 1], lcur[NBK], goff[NBK];
  __shared__ int tmp[256];
  const int tid = threadIdx.x;
  if (tid < NBK) lhist[tid] = 0;
  __syncthreads();
  const int e0 = blockIdx.x * EPB;
#pragma unroll
  for (int i = 0; i < EPB / 256; ++i) {
    int e = e0 + i * 256 + tid;
    unsigned p = 0xFFFFFFFFu;
    if (e < NE) {
      int s = ei[e], d = ei[NE + e];
      p = ((unsigned)(d >> 8) << 24) | ((unsigned)(d & 255) << 16) | (unsigned)s;
      atomicAdd(&lhist[d >> 8], 1);
    }
    lin[i * 256 + tid] = p;
  }
  __syncthreads();
  int v = (tid < NBK) ? lhist[tid] : 0;
  tmp[tid] = v;
  __syncthreads();
  for (int off = 1; off < 256; off <<= 1) {
    int t = (tid >= off) ? tmp[tid - off] : 0;
    __syncthreads();
    tmp[tid] += t;
    __syncthreads();
  }
  if (tid < NBK) { lbase[tid] = tmp[tid] - v; lcur[tid] = tmp[tid] - v; }
  if (tid == NBK - 1) lbase[NBK] = tmp[NBK - 1];
  __syncthreads();
#pragma unroll
  for (int i = 0; i < EPB / 256; ++i) {
    unsigned p = lin[i * 256 + tid];
    if (p != 0xFFFFFFFFu) {
      int b = p >> 24;
      int pos = atomicAdd(&lcur[b], 1);
      lout[pos] = p;                           // keep bucket byte for direct lookup
    }
  }
  if (tid < NBK) goff[tid] = atomicAdd(&gcur[tid], lhist[tid]);
  __syncthreads();
  const int total = lbase[NBK];
  for (int i = tid; i < total; i += 256) {
    unsigned p = lout[i];
    int b = p >> 24;                           // direct: no search
    gbuf[(size_t)b * BCAP + goff[b] + (i - lbase[b])] = p & 0xFFFFFFu;
  }
}

// ============ pass 2: fused bucket-base scan + per-bucket counting sort ============
__global__ void p2_sort(const unsigned* __restrict__ gbuf, const int* __restrict__ gcur,
                        int* __restrict__ bbase_out, int* __restrict__ rp,
                        unsigned* __restrict__ spk) {
  __shared__ unsigned lin[BCAP];
  __shared__ unsigned lsorted[BCAP];
  __shared__ int lhist[256], lcur2[256], tmp[256], sscan[256];
  const int tid = threadIdx.x;
  const int b = blockIdx.x;
  int gv = (tid < NBK) ? gcur[tid] : 0;
  tmp[tid] = gv;
  __syncthreads();
  for (int off = 1; off < 256; off <<= 1) {
    int t = (tid >= off) ? tmp[tid - off] : 0;
    __syncthreads();
    tmp[tid] += t;
    __syncthreads();
  }
  sscan[tid] = tmp[tid];
  __syncthreads();
  const int base = b ? sscan[b - 1] : 0;
  const int cnt = min(gcur[b], BCAP);
  if (tid == 0) { bbase_out[b] = base; if (b == 0) rp[NN] = NE; }
  lhist[tid] = 0;
  __syncthreads();
  for (int i = tid; i < cnt; i += 256) {
    unsigned p = gbuf[(size_t)b * BCAP + i];
    lin[i] = p;
    atomicAdd(&lhist[(p >> 16) & 255], 1);
  }
  __syncthreads();
  int v = lhist[tid];
  tmp[tid] = v;
  __syncthreads();
  for (int off = 1; off < 256; off <<= 1) {
    int t = (tid >= off) ? tmp[tid - off] : 0;
    __syncthreads();
    tmp[tid] += t;
    __syncthreads();
  }
  lcur2[tid] = tmp[tid] - v;
  int node = b * 256 + tid;
  if (node < NN) rp[node] = base + tmp[tid] - v;
  __syncthreads();
  for (int i = tid; i < cnt; i += 256) {
    unsigned p = lin[i];
    int pos = atomicAdd(&lcur2[(p >> 16) & 255], 1);
    lsorted[pos] = p & 0xFFFFFFu;
  }
  __syncthreads();
  for (int i = tid; i < cnt; i += 256) spk[base + i] = lsorted[i];
}

// ============ W transposes to fp16 (x consumed f32 directly by layer-1 GEMM) ============
__global__ void wcast(const float* __restrict__ W1, const float* __restrict__ W2,
                      const float* __restrict__ W3, _Float16* __restrict__ WT1,
                      _Float16* __restrict__ WT2, _Float16* __restrict__ WT3) {
  int i = blockIdx.x * 256 + threadIdx.x;
  if (i < 16384)             { int k = i >> 7, c = i & 127; WT1[c * 128 + k] = (_Float16)W1[i]; }
  else if (i < 32768)        { int j = i - 16384; int k = j >> 7, c = j & 127; WT2[c * 128 + k] = (_Float16)W2[j]; }
  else if (i < 32768 + 4096) { int j = i - 32768; int k = j >> 5, c = j & 31;  WT3[c * 128 + k] = (_Float16)W3[j]; }
}

// ============ MFMA GEMM (K=128): fp16 compute, f32 accum; fused attn coefs; FLAT output ============
template <int CN, bool F32IN>   // CN = 128 (H=4) or 32 (H=1)
__global__ void __launch_bounds__(256)
gemm_mfma(const void* __restrict__ Xv, const _Float16* __restrict__ WT,
          const float* __restrict__ aS, const float* __restrict__ aD,
          _Float16* __restrict__ Hout, float* __restrict__ alS, float* __restrict__ alD) {
  __shared__ _Float16 xt[16 * 64 * 8];
  __shared__ _Float16 wt[16 * CN * 8];
  const int tid = threadIdx.x;
  const int row0 = blockIdx.x * 64;
  {
    int r = tid >> 2, qq = tid & 3;
    int gr = row0 + r;
#pragma unroll
    for (int s = 0; s < 4; ++s) {
      h8 v = {};
      if (gr < NN) {
        if constexpr (F32IN) {
          const float* src = (const float*)Xv + (size_t)gr * 128 + qq * 32 + s * 8;
          float4 a = *(const float4*)src;
          float4 b = *(const float4*)(src + 4);
          v = h8{(_Float16)a.x, (_Float16)a.y, (_Float16)a.z, (_Float16)a.w,
                 (_Float16)b.x, (_Float16)b.y, (_Float16)b.z, (_Float16)b.w};
        } else {
          v = *(const h8*)((const _Float16*)Xv + (size_t)gr * 128 + qq * 32 + s * 8);
        }
      }
      *(h8*)&xt[((qq * 4 + s) * 64 + r) * 8] = v;
    }
  }
  if constexpr (CN == 128) {
    int col = tid >> 1, q = tid & 1;
#pragma unroll
    for (int s = 0; s < 8; ++s) {
      int kc = q * 8 + s;
      *(h8*)&wt[(kc * CN + col) * 8] = *(const h8*)(WT + col * 128 + q * 64 + s * 8);
    }
  } else {
    int col = tid >> 3, q = tid & 7;
#pragma unroll
    for (int s = 0; s < 2; ++s) {
      int kc = q * 2 + s;
      *(h8*)&wt[(kc * CN + col) * 8] = *(const h8*)(WT + col * 128 + q * 16 + s * 8);
    }
  }
  __syncthreads();
  const int w = tid >> 6, ln = tid & 15, lg = (tid & 63) >> 4;
  if constexpr (CN == 128) {
    f32x4 acc[4][2] = {};
#pragma unroll
    for (int ks = 0; ks < 4; ++ks) {
      int kc = ks * 4 + lg;
      h8 a[4], b[2];
#pragma unroll
      for (int mt = 0; mt < 4; ++mt) a[mt] = *(const h8*)&xt[(kc * 64 + mt * 16 + ln) * 8];
#pragma unroll
      for (int nt = 0; nt < 2; ++nt) b[nt] = *(const h8*)&wt[(kc * CN + w * 32 + nt * 16 + ln) * 8];
#pragma unroll
      for (int mt = 0; mt < 4; ++mt)
#pragma unroll
        for (int nt = 0; nt < 2; ++nt)
          acc[mt][nt] = __builtin_amdgcn_mfma_f32_16x16x32_f16(a[mt], b[nt], acc[mt][nt], 0, 0, 0);
    }
    int c0 = w * 32 + ln, c1 = c0 + 16;
    float as0 = aS[c0], as1 = aS[c1], ad0 = aD[c0], ad1 = aD[c1];
#pragma unroll
    for (int mt = 0; mt < 4; ++mt) {
#pragma unroll
      for (int i = 0; i < 4; ++i) {
        int row = row0 + mt * 16 + lg * 4 + i;
        float d0 = acc[mt][0][i], d1 = acc[mt][1][i];
        float ps = d0 * as0 + d1 * as1;
        float pd = d0 * ad0 + d1 * ad1;
        ps += __shfl_xor(ps, 1, 64); pd += __shfl_xor(pd, 1, 64);
        ps += __shfl_xor(ps, 2, 64); pd += __shfl_xor(pd, 2, 64);
        ps += __shfl_xor(ps, 4, 64); pd += __shfl_xor(pd, 4, 64);
        ps += __shfl_xor(ps, 8, 64); pd += __shfl_xor(pd, 8, 64);
        if (row < NN) {
          Hout[(size_t)row * 128 + c0] = (_Float16)d0;
          Hout[(size_t)row * 128 + c1] = (_Float16)d1;
          if (ln == 0) { alS[row * 4 + w] = ps; alD[row * 4 + w] = pd; }
        }
      }
    }
  } else {
    f32x4 acc[2] = {};
#pragma unroll
    for (int ks = 0; ks < 4; ++ks) {
      int kc = ks * 4 + lg;
      h8 a = *(const h8*)&xt[(kc * 64 + w * 16 + ln) * 8];
#pragma unroll
      for (int nt = 0; nt < 2; ++nt) {
        h8 b = *(const h8*)&wt[(kc * CN + nt * 16 + ln) * 8];
        acc[nt] = __builtin_amdgcn_mfma_f32_16x16x32_f16(a, b, acc[nt], 0, 0, 0);
      }
    }
    int c0 = ln, c1 = ln + 16;
    float as0 = aS[c0], as1 = aS[c1], ad0 = aD[c0], ad1 = aD[c1];
#pragma unroll
    for (int i = 0; i < 4; ++i) {
      int row = row0 + w * 16 + lg * 4 + i;
      float d0 = acc[0][i], d1 = acc[1][i];
      float ps = d0 * as0 + d1 * as1;
      float pd = d0 * ad0 + d1 * ad1;
      ps += __shfl_xor(ps, 1, 64); pd += __shfl_xor(pd, 1, 64);
      ps += __shfl_xor(ps, 2, 64); pd += __shfl_xor(pd, 2, 64);
      ps += __shfl_xor(ps, 4, 64); pd += __shfl_xor(pd, 4, 64);
      ps += __shfl_xor(ps, 8, 64); pd += __shfl_xor(pd, 8, 64);
      if (row < NN) {
        Hout[(size_t)row * 32 + c0] = (_Float16)d0;
        Hout[(size_t)row * 32 + c1] = (_Float16)d1;
        if (ln == 0) { alS[row] = ps; alD[row] = pd; }
      }
    }
  }
}

// ===== fused softmax+agg H=4, WIDE loads: one wave/node; 8x dwordx2 gathers per chunk =====
// Stats role (r11): lane = (hh = lane>>4) * 16 + (el = lane&15); packed (ev16|src) per edge/head.
// Compute role: cl = lane&31 owns channels 4cl..4cl+3 (head chd = cl>>3); half = lane>>5 takes
// edges 2i+half. Halves are summed by a final xor-32 reduce; lanes 0-31 write the row.
__global__ void gat_agg_h4(const int* __restrict__ rp, const unsigned* __restrict__ spk,
                           const __half2* __restrict__ Hf2, const float* __restrict__ alS,
                           const float* __restrict__ alD, const float* __restrict__ bias,
                           __half2* __restrict__ outf) {
  int node = (blockIdx.x * 256 + threadIdx.x) >> 6;
  int lane = threadIdx.x & 63;
  if (node >= NN) return;
  int beg = rp[node], end = rp[node + 1];
  const int el = lane & 15, hh = lane >> 4;     // stats mapping
  const int cl = lane & 31, half = lane >> 5;   // compute mapping
  const int chd = cl >> 3;                      // head of my 4 channels
  float ad_h = alD[node * 4 + hh];
  float acc0 = 0.f, acc1 = 0.f, acc2 = 0.f, acc3 = 0.f, sm = 0.f;
  for (int ch = beg; ch < end; ch += 16) {
    int cnt = end - ch;
    unsigned pk = (unsigned)node;               // ev bits = 0 -> alpha 0, safe gather idx
    if (el < cnt) {
      int sv = (int)(spk[ch + el] & 0xFFFFu);
      float x = alS[sv * 4 + hh] + ad_h;
      x = x > 0.f ? x : SLOPE * x;
      float ev = __expf(x);
      sm += ev;
      pk = ((unsigned)__half_as_ushort(__float2half(ev)) << 16) | (unsigned)sv;
    }
    unsigned parr[8];
#pragma unroll
    for (int i = 0; i < 8; ++i)                 // my edge (2i+half), my head chd
      parr[i] = __shfl(pk, chd * 16 + 2 * i + half, 64);
    h2x2 hv[8];
#pragma unroll
    for (int i = 0; i < 8; ++i)                 // 8 x 8B gathers in flight
      hv[i] = *(const h2x2*)(Hf2 + (size_t)(parr[i] & 0xFFFFu) * 64 + 2 * cl);
#pragma unroll
    for (int i = 0; i < 8; ++i) {
      float a = __half2float(__ushort_as_half((unsigned short)(parr[i] >> 16)));
      float2 f0 = __half22float2(hv[i].a), f1 = __half22float2(hv[i].b);
      acc0 = fmaf(f0.x, a, acc0);
      acc1 = fmaf(f0.y, a, acc1);
      acc2 = fmaf(f1.x, a, acc2);
      acc3 = fmaf(f1.y, a, acc3);
    }
  }
  // combine edge-halves (lanes l and l+32 hold the same channels)
  acc0 += __shfl_xor(acc0, 32, 64);
  acc1 += __shfl_xor(acc1, 32, 64);
  acc2 += __shfl_xor(acc2, 32, 64);
  acc3 += __shfl_xor(acc3, 32, 64);
#pragma unroll
  for (int off = 8; off >= 1; off >>= 1) sm += __shfl_xor(sm, off, 64);  // per-head denom
  float smh = __shfl(sm, chd * 16, 64);         // my head's denominator (no self yet)
  if (lane < 32) {
    float xs = alS[node * 4 + chd] + alD[node * 4 + chd];   // self-loop analytic
    xs = xs > 0.f ? xs : SLOPE * xs;
    float evs = __expf(xs);
    h2x2 hs = *(const h2x2*)(Hf2 + (size_t)node * 64 + 2 * cl);
    float2 s0 = __half22float2(hs.a), s1 = __half22float2(hs.b);
    float inv = 1.0f / (smh + evs);
    float v0 = (acc0 + s0.x * evs) * inv + bias[4 * cl + 0];
    float v1 = (acc1 + s0.y * evs) * inv + bias[4 * cl + 1];
    float v2 = (acc2 + s1.x * evs) * inv + bias[4 * cl + 2];
    float v3 = (acc3 + s1.y * evs) * inv + bias[4 * cl + 3];
    v0 = v0 > 0.f ? v0 : expm1f(v0);
    v1 = v1 > 0.f ? v1 : expm1f(v1);
    v2 = v2 > 0.f ? v2 : expm1f(v2);
    v3 = v3 > 0.f ? v3 : expm1f(v3);
    h2x2 o;
    o.a = __floats2half2_rn(v0, v1);
    o.b = __floats2half2_rn(v2, v3);
    *(h2x2*)(outf + (size_t)node * 64 + 2 * cl) = o;
  }
}

// ===== fused softmax+agg H=1 (F=32): 16 lanes/node, packed single shfl (r11) =====
__global__ void gat_agg_h1(const int* __restrict__ rp, const unsigned* __restrict__ spk,
                           const __half2* __restrict__ Hf2, const float* __restrict__ alS,
                           const float* __restrict__ alD, const float* __restrict__ bias,
                           __half2* __restrict__ outf) {
  int node = (blockIdx.x * 256 + threadIdx.x) >> 4;
  int lane = threadIdx.x & 15;
  if (node >= NN) return;
  int beg = rp[node], end = rp[node + 1];
  float ad = alD[node];
  float xsf = alS[node] + ad;
  xsf = xsf > 0.f ? xsf : SLOPE * xsf;
  float evs = __expf(xsf);
  __half2 hself = Hf2[(size_t)node * 16 + lane];
  float accx = __low2float(hself) * evs;
  float accy = __high2float(hself) * evs;
  float sm = (lane == 0) ? evs : 0.f;
  for (int ch = beg; ch < end; ch += 16) {
    int cnt = end - ch;
    unsigned pk = (unsigned)node;
    if (lane < cnt) {
      int sv = (int)(spk[ch + lane] & 0xFFFFu);
      float x = alS[sv] + ad;
      x = x > 0.f ? x : SLOPE * x;
      float ev = __expf(x);
      sm += ev;
      unsigned evb = (unsigned)__half_as_ushort(__float2half(ev));
      pk = (evb << 16) | (unsigned)sv;
    }
    unsigned parr[16];
#pragma unroll
    for (int e = 0; e < 16; ++e) parr[e] = __shfl(pk, e, 16);
    __half2 hv[16];
#pragma unroll
    for (int e = 0; e < 16; ++e)
      hv[e] = Hf2[(size_t)(parr[e] & 0xFFFFu) * 16 + lane];
#pragma unroll
    for (int e = 0; e < 16; ++e) {
      float a = __half2float(__ushort_as_half((unsigned short)(parr[e] >> 16)));
      float2 f = __half22float2(hv[e]);
      accx = fmaf(f.x, a, accx);
      accy = fmaf(f.y, a, accy);
    }
  }
#pragma unroll
  for (int off = 8; off >= 1; off >>= 1) sm += __shfl_xor(sm, off, 16);
  float inv = 1.0f / sm;
  float vx = accx * inv + bias[2 * lane];
  float vy = accy * inv + bias[2 * lane + 1];
  vx = vx > 0.f ? vx : expm1f(vx);
  vy = vy > 0.f ? vy : expm1f(vy);
  outf[(size_t)node * 16 + lane] = __floats2half2_rn(vx, vy);
}

// ======================= fused pool (sorted batch) + mu/logvar heads =======================
__device__ __forceinline__ int lb_batch(const int* __restrict__ b, int val) {
  int lo = 0, hi = NN;
  while (lo < hi) { int mid = (lo + hi) >> 1; if (b[mid] < val) lo = mid + 1; else hi = mid; }
  return lo;
}

__global__ void pool_head(const __half2* __restrict__ feat, const int* __restrict__ batch,
                          const float* __restrict__ Wmu, const float* __restrict__ bmu,
                          const float* __restrict__ Wlv, const float* __restrict__ blv,
                          float* __restrict__ out) {
  int g = blockIdx.x;
  int start = lb_batch(batch, g), end = lb_batch(batch, g + 1);
  int cp = threadIdx.x & 15, sub = threadIdx.x >> 4;
  float ax = 0.f, ay = 0.f;
  for (int n = start + sub; n < end; n += 16) {
    __half2 v = feat[(size_t)n * 16 + cp];
    ax += __low2float(v);
    ay += __high2float(v);
  }
  __shared__ float red[16][32];
  __shared__ float pl[32];
  red[sub][2 * cp] = ax;
  red[sub][2 * cp + 1] = ay;
  __syncthreads();
  if (threadIdx.x < 32) {
    float s = 0.f;
#pragma unroll
    for (int i = 0; i < 16; ++i) s += red[i][threadIdx.x];
    pl[threadIdx.x] = s / fmaxf((float)(end - start), 1.0f);
  }
  __syncthreads();
  if (threadIdx.x < NLAT) {
    int l = threadIdx.x;
    float mu = bmu[l], lv = blv[l];
#pragma unroll
    for (int k = 0; k < 32; ++k) {
      float p = pl[k];
      mu = fmaf(p, Wmu[k * NLAT + l], mu);
      lv = fmaf(p, Wlv[k * NLAT + l], lv);
    }
    out[g * NLAT + l] = mu;
    out[NG * NLAT + g * NLAT + l] = lv;
  }
}

extern "C" void kernel_launch(void* const* d_in, const int* in_sizes, int n_in,
                              void* d_out, int out_size, void* d_ws, size_t ws_size,
                              hipStream_t stream) {
  const float* x     = (const float*)d_in[0];
  const float* W1    = (const float*)d_in[1];
  const float* as1   = (const float*)d_in[2];
  const float* ad1   = (const float*)d_in[3];
  const float* b1    = (const float*)d_in[4];
  const float* W2    = (const float*)d_in[5];
  const float* as2   = (const float*)d_in[6];
  const float* ad2   = (const float*)d_in[7];
  const float* b2    = (const float*)d_in[8];
  const float* W3    = (const float*)d_in[9];
  const float* as3   = (const float*)d_in[10];
  const float* ad3   = (const float*)d_in[11];
  const float* b3    = (const float*)d_in[12];
  const float* Wmu   = (const float*)d_in[13];
  const float* bmu   = (const float*)d_in[14];
  const float* Wlv   = (const float*)d_in[15];
  const float* blv   = (const float*)d_in[16];
  const int*   ei    = (const int*)d_in[17];
  const int*   batch = (const int*)d_in[18];
  float* out = (float*)d_out;

  _Float16* A   = (_Float16*)d_ws;                  // [N,128] fp16 h (gemm out, flat)
  _Float16* Bh  = A + (size_t)NN * 128;             // [N,128] fp16 features
  float* alS    = (float*)(Bh + (size_t)NN * 128);  // [N,4]
  float* alD    = alS + (size_t)NN * 4;             // [N,4]
  _Float16* WT1 = (_Float16*)(alD + (size_t)NN * 4);// [128*128]
  _Float16* WT2 = WT1 + 16384;                      // [128*128]
  _Float16* WT3 = WT2 + 16384;                      // [32*128]
  int* rp       = (int*)(WT3 + 4096);               // [N+1]
  int* gcur     = rp + NN + 1;                      // [256]
  int* bbase    = gcur + 256;                       // [256]
  unsigned* gbuf = (unsigned*)(bbase + 256);        // [NBK*BCAP]
  unsigned* spk  = gbuf + (size_t)NBK * BCAP;       // [NE] packed (dlocal<<16|src)

  dim3 blk(256);

  // ---------------- CSR build + weight prep ----------------
  hipMemsetAsync(gcur, 0, 256 * sizeof(int), stream);
  p1_bucket<<<NB1, blk, 0, stream>>>(ei, gcur, gbuf);
  p2_sort<<<NBK, blk, 0, stream>>>(gbuf, gcur, bbase, rp, spk);
  wcast<<<144, blk, 0, stream>>>(W1, W2, W3, WT1, WT2, WT3);

  const int GB = (NN + 63) / 64;
  // ---------------- layer 1 (f32 x input) ----------------
  gemm_mfma<128, true><<<GB, blk, 0, stream>>>(x, WT1, as1, ad1, A, alS, alD);
  gat_agg_h4<<<(NN * 64) / 256, blk, 0, stream>>>(rp, spk, (const __half2*)A, alS, alD, b1, (__half2*)Bh);
  // ---------------- layer 2 ----------------
  gemm_mfma<128, false><<<GB, blk, 0, stream>>>(Bh, WT2, as2, ad2, A, alS, alD);
  gat_agg_h4<<<(NN * 64) / 256, blk, 0, stream>>>(rp, spk, (const __half2*)A, alS, alD, b2, (__half2*)Bh);
  // ---------------- layer 3 ----------------
  gemm_mfma<32, false><<<GB, blk, 0, stream>>>(Bh, WT3, as3, ad3, A, alS, alD);
  gat_agg_h1<<<(NN * 16) / 256, blk, 0, stream>>>(rp, spk, (const __half2*)A, alS, alD, b3, (__half2*)Bh);

  // ---------------- fused pool + heads ----------------
  pool_head<<<NG, blk, 0, stream>>>((const __half2*)Bh, batch, Wmu, bmu, Wlv, blv, out);
}

// Round 15
// 189.440 us; speedup vs baseline: 1.4421x; 1.0144x over previous
//
#include <hip/hip_runtime.h>
#include <hip/hip_fp16.h>

constexpr int NN   = 50000;            // nodes
constexpr int NE   = 800000;           // edges (self-loops handled analytically)
constexpr int NG   = 512;              // graphs
constexpr int NLAT = 64;               // latent dim
constexpr float SLOPE = 0.2f;          // leaky relu slope

constexpr int NBK  = 196;              // coarse buckets of 256 nodes
constexpr int BCAP = 8192;             // per-bucket capacity
constexpr int EPB  = 4096;             // edges per pass-1 block
constexpr int NB1  = (NE + EPB - 1) / EPB;   // 196

typedef _Float16 h8 __attribute__((ext_vector_type(8)));
typedef float f32x4 __attribute__((ext_vector_type(4)));

// ============ pass 1: bucket edges by dst>>8; direct-bucket copy-out ============
__global__ void p1_bucket(const int* __restrict__ ei, int* __restrict__ gcur,
                          unsigned* __restrict__ gbuf) {
  __shared__ unsigned lin[EPB];
  __shared__ unsigned lout[EPB];
  __shared__ int lhist[NBK], lbase[NBK + 1], lcur[NBK], goff[NBK];
  __shared__ int tmp[256];
  const int tid = threadIdx.x;
  if (tid < NBK) lhist[tid] = 0;
  __syncthreads();
  const int e0 = blockIdx.x * EPB;
#pragma unroll
  for (int i = 0; i < EPB / 256; ++i) {
    int e = e0 + i * 256 + tid;
    unsigned p = 0xFFFFFFFFu;
    if (e < NE) {
      int s = ei[e], d = ei[NE + e];
      p = ((unsigned)(d >> 8) << 24) | ((unsigned)(d & 255) << 16) | (unsigned)s;
      atomicAdd(&lhist[d >> 8], 1);
    }
    lin[i * 256 + tid] = p;
  }
  __syncthreads();
  int v = (tid < NBK) ? lhist[tid] : 0;
  tmp[tid] = v;
  __syncthreads();
  for (int off = 1; off < 256; off <<= 1) {
    int t = (tid >= off) ? tmp[tid - off] : 0;
    __syncthreads();
    tmp[tid] += t;
    __syncthreads();
  }
  if (tid < NBK) { lbase[tid] = tmp[tid] - v; lcur[tid] = tmp[tid] - v; }
  if (tid == NBK - 1) lbase[NBK] = tmp[NBK - 1];
  __syncthreads();
#pragma unroll
  for (int i = 0; i < EPB / 256; ++i) {
    unsigned p = lin[i * 256 + tid];
    if (p != 0xFFFFFFFFu) {
      int b = p >> 24;
      int pos = atomicAdd(&lcur[b], 1);
      lout[pos] = p;                           // keep bucket byte for direct lookup
    }
  }
  if (tid < NBK) goff[tid] = atomicAdd(&gcur[tid], lhist[tid]);
  __syncthreads();
  const int total = lbase[NBK];
  for (int i = tid; i < total; i += 256) {
    unsigned p = lout[i];
    int b = p >> 24;
    gbuf[(size_t)b * BCAP + goff[b] + (i - lbase[b])] = p & 0xFFFFFFu;
  }
}

// ============ pass 2: fused bucket-base scan + per-bucket counting sort ============
__global__ void p2_sort(const unsigned* __restrict__ gbuf, const int* __restrict__ gcur,
                        int* __restrict__ bbase_out, int* __restrict__ rp,
                        unsigned* __restrict__ spk) {
  __shared__ unsigned lin[BCAP];
  __shared__ unsigned lsorted[BCAP];
  __shared__ int lhist[256], lcur2[256], tmp[256], sscan[256];
  const int tid = threadIdx.x;
  const int b = blockIdx.x;
  int gv = (tid < NBK) ? gcur[tid] : 0;
  tmp[tid] = gv;
  __syncthreads();
  for (int off = 1; off < 256; off <<= 1) {
    int t = (tid >= off) ? tmp[tid - off] : 0;
    __syncthreads();
    tmp[tid] += t;
    __syncthreads();
  }
  sscan[tid] = tmp[tid];
  __syncthreads();
  const int base = b ? sscan[b - 1] : 0;
  const int cnt = min(gcur[b], BCAP);
  if (tid == 0) { bbase_out[b] = base; if (b == 0) rp[NN] = NE; }
  lhist[tid] = 0;
  __syncthreads();
  for (int i = tid; i < cnt; i += 256) {
    unsigned p = gbuf[(size_t)b * BCAP + i];
    lin[i] = p;
    atomicAdd(&lhist[(p >> 16) & 255], 1);
  }
  __syncthreads();
  int v = lhist[tid];
  tmp[tid] = v;
  __syncthreads();
  for (int off = 1; off < 256; off <<= 1) {
    int t = (tid >= off) ? tmp[tid - off] : 0;
    __syncthreads();
    tmp[tid] += t;
    __syncthreads();
  }
  lcur2[tid] = tmp[tid] - v;
  int node = b * 256 + tid;
  if (node < NN) rp[node] = base + tmp[tid] - v;
  __syncthreads();
  for (int i = tid; i < cnt; i += 256) {
    unsigned p = lin[i];
    int pos = atomicAdd(&lcur2[(p >> 16) & 255], 1);
    lsorted[pos] = p & 0xFFFFFFu;
  }
  __syncthreads();
  for (int i = tid; i < cnt; i += 256) spk[base + i] = lsorted[i];
}

// ============ W transposes to fp16 ============
__global__ void wcast(const float* __restrict__ W1, const float* __restrict__ W2,
                      const float* __restrict__ W3, _Float16* __restrict__ WT1,
                      _Float16* __restrict__ WT2, _Float16* __restrict__ WT3) {
  int i = blockIdx.x * 256 + threadIdx.x;
  if (i < 16384)             { int k = i >> 7, c = i & 127; WT1[c * 128 + k] = (_Float16)W1[i]; }
  else if (i < 32768)        { int j = i - 16384; int k = j >> 7, c = j & 127; WT2[c * 128 + k] = (_Float16)W2[j]; }
  else if (i < 32768 + 4096) { int j = i - 32768; int k = j >> 5, c = j & 31;  WT3[c * 128 + k] = (_Float16)W3[j]; }
}

// ============ MFMA GEMM (K=128): fp16 compute, f32 accum; fused attn coefs ============
template <int CN, bool F32IN>   // CN = 128 (H=4) or 32 (H=1)
__global__ void __launch_bounds__(256)
gemm_mfma(const void* __restrict__ Xv, const _Float16* __restrict__ WT,
          const float* __restrict__ aS, const float* __restrict__ aD,
          _Float16* __restrict__ Hout, float* __restrict__ alS, float* __restrict__ alD) {
  __shared__ _Float16 xt[16 * 64 * 8];
  __shared__ _Float16 wt[16 * CN * 8];
  const int tid = threadIdx.x;
  const int row0 = blockIdx.x * 64;
  {
    int r = tid >> 2, qq = tid & 3;
    int gr = row0 + r;
#pragma unroll
    for (int s = 0; s < 4; ++s) {
      h8 v = {};
      if (gr < NN) {
        if constexpr (F32IN) {
          const float* src = (const float*)Xv + (size_t)gr * 128 + qq * 32 + s * 8;
          float4 a = *(const float4*)src;
          float4 b = *(const float4*)(src + 4);
          v = h8{(_Float16)a.x, (_Float16)a.y, (_Float16)a.z, (_Float16)a.w,
                 (_Float16)b.x, (_Float16)b.y, (_Float16)b.z, (_Float16)b.w};
        } else {
          v = *(const h8*)((const _Float16*)Xv + (size_t)gr * 128 + qq * 32 + s * 8);
        }
      }
      *(h8*)&xt[((qq * 4 + s) * 64 + r) * 8] = v;
    }
  }
  if constexpr (CN == 128) {
    int col = tid >> 1, q = tid & 1;
#pragma unroll
    for (int s = 0; s < 8; ++s) {
      int kc = q * 8 + s;
      *(h8*)&wt[(kc * CN + col) * 8] = *(const h8*)(WT + col * 128 + q * 64 + s * 8);
    }
  } else {
    int col = tid >> 3, q = tid & 7;
#pragma unroll
    for (int s = 0; s < 2; ++s) {
      int kc = q * 2 + s;
      *(h8*)&wt[(kc * CN + col) * 8] = *(const h8*)(WT + col * 128 + q * 16 + s * 8);
    }
  }
  __syncthreads();
  const int w = tid >> 6, ln = tid & 15, lg = (tid & 63) >> 4;
  if constexpr (CN == 128) {
    f32x4 acc[4][2] = {};
#pragma unroll
    for (int ks = 0; ks < 4; ++ks) {
      int kc = ks * 4 + lg;
      h8 a[4], b[2];
#pragma unroll
      for (int mt = 0; mt < 4; ++mt) a[mt] = *(const h8*)&xt[(kc * 64 + mt * 16 + ln) * 8];
#pragma unroll
      for (int nt = 0; nt < 2; ++nt) b[nt] = *(const h8*)&wt[(kc * CN + w * 32 + nt * 16 + ln) * 8];
#pragma unroll
      for (int mt = 0; mt < 4; ++mt)
#pragma unroll
        for (int nt = 0; nt < 2; ++nt)
          acc[mt][nt] = __builtin_amdgcn_mfma_f32_16x16x32_f16(a[mt], b[nt], acc[mt][nt], 0, 0, 0);
    }
    int c0 = w * 32 + ln, c1 = c0 + 16;
    float as0 = aS[c0], as1 = aS[c1], ad0 = aD[c0], ad1 = aD[c1];
#pragma unroll
    for (int mt = 0; mt < 4; ++mt) {
#pragma unroll
      for (int i = 0; i < 4; ++i) {
        int row = row0 + mt * 16 + lg * 4 + i;
        float d0 = acc[mt][0][i], d1 = acc[mt][1][i];
        float ps = d0 * as0 + d1 * as1;
        float pd = d0 * ad0 + d1 * ad1;
        ps += __shfl_xor(ps, 1, 64); pd += __shfl_xor(pd, 1, 64);
        ps += __shfl_xor(ps, 2, 64); pd += __shfl_xor(pd, 2, 64);
        ps += __shfl_xor(ps, 4, 64); pd += __shfl_xor(pd, 4, 64);
        ps += __shfl_xor(ps, 8, 64); pd += __shfl_xor(pd, 8, 64);
        if (row < NN) {
          Hout[(size_t)row * 128 + c0] = (_Float16)d0;
          Hout[(size_t)row * 128 + c1] = (_Float16)d1;
          if (ln == 0) { alS[row * 4 + w] = ps; alD[row * 4 + w] = pd; }
        }
      }
    }
  } else {
    f32x4 acc[2] = {};
#pragma unroll
    for (int ks = 0; ks < 4; ++ks) {
      int kc = ks * 4 + lg;
      h8 a = *(const h8*)&xt[(kc * 64 + w * 16 + ln) * 8];
#pragma unroll
      for (int nt = 0; nt < 2; ++nt) {
        h8 b = *(const h8*)&wt[(kc * CN + nt * 16 + ln) * 8];
        acc[nt] = __builtin_amdgcn_mfma_f32_16x16x32_f16(a, b, acc[nt], 0, 0, 0);
      }
    }
    int c0 = ln, c1 = ln + 16;
    float as0 = aS[c0], as1 = aS[c1], ad0 = aD[c0], ad1 = aD[c1];
#pragma unroll
    for (int i = 0; i < 4; ++i) {
      int row = row0 + w * 16 + lg * 4 + i;
      float d0 = acc[0][i], d1 = acc[1][i];
      float ps = d0 * as0 + d1 * as1;
      float pd = d0 * ad0 + d1 * ad1;
      ps += __shfl_xor(ps, 1, 64); pd += __shfl_xor(pd, 1, 64);
      ps += __shfl_xor(ps, 2, 64); pd += __shfl_xor(pd, 2, 64);
      ps += __shfl_xor(ps, 4, 64); pd += __shfl_xor(pd, 4, 64);
      ps += __shfl_xor(ps, 8, 64); pd += __shfl_xor(pd, 8, 64);
      if (row < NN) {
        Hout[(size_t)row * 32 + c0] = (_Float16)d0;
        Hout[(size_t)row * 32 + c1] = (_Float16)d1;
        if (ln == 0) { alS[row] = ps; alD[row] = pd; }
      }
    }
  }
}

// ===== fused softmax+agg H=4 (r11 mapping) with software-pipelined stats =====
// lane covers channel pair (2*lane, 2*lane+1); head = lane>>4 = stats-lane head hh.
// Chunk i+1's packed (ev16|src) word (spk load + alS gather + exp) is computed BEFORE
// chunk i's shfl/gather/FMA so its ~500-cycle load chain overlaps chunk i's work.
__global__ void gat_agg_h4(const int* __restrict__ rp, const unsigned* __restrict__ spk,
                           const __half2* __restrict__ Hf2, const float* __restrict__ alS,
                           const float* __restrict__ alD, const float* __restrict__ bias,
                           __half2* __restrict__ outf) {
  int node = (blockIdx.x * 256 + threadIdx.x) >> 6;
  int lane = threadIdx.x & 63;
  if (node >= NN) return;
  int beg = rp[node], end = rp[node + 1];
  int el = lane & 15, hh = lane >> 4;
  const int hb = lane & 48;                     // head-group base for shfl
  float ad_h = alD[node * 4 + hh];
  float sm = 0.f;
  auto mk = [&](int ch) -> unsigned {           // stats for one chunk (updates sm)
    unsigned pk = (unsigned)node;               // ev bits = 0 -> alpha 0, safe gather idx
    if (el < end - ch) {
      int sv = (int)(spk[ch + el] & 0xFFFFu);
      float x = alS[sv * 4 + hh] + ad_h;
      x = x > 0.f ? x : SLOPE * x;
      float ev = __expf(x);
      sm += ev;
      pk = ((unsigned)__half_as_ushort(__float2half(ev)) << 16) | (unsigned)sv;
    }
    return pk;
  };
  unsigned pkc = (beg < end) ? mk(beg) : (unsigned)node;
  // self-loop analytic (loads overlap first chunk's stats chain)
  float xsf = alS[node * 4 + hh] + ad_h;
  xsf = xsf > 0.f ? xsf : SLOPE * xsf;
  float evs = __expf(xsf);
  __half2 hself = Hf2[(size_t)node * 64 + lane];
  float accx = __low2float(hself) * evs;
  float accy = __high2float(hself) * evs;
  if (el == 0) sm += evs;
  for (int ch = beg; ch < end; ch += 16) {
    unsigned pkn = (ch + 16 < end) ? mk(ch + 16) : (unsigned)node;  // prefetch next stats
    unsigned parr[16];
#pragma unroll
    for (int e = 0; e < 16; ++e) parr[e] = __shfl(pkc, hb + e, 64); // 1 shfl/edge
    __half2 hv[16];
#pragma unroll
    for (int e = 0; e < 16; ++e)                // 16 row gathers in flight
      hv[e] = Hf2[(size_t)(parr[e] & 0xFFFFu) * 64 + lane];
#pragma unroll
    for (int e = 0; e < 16; ++e) {
      float a = __half2float(__ushort_as_half((unsigned short)(parr[e] >> 16)));
      float2 f = __half22float2(hv[e]);
      accx = fmaf(f.x, a, accx);
      accy = fmaf(f.y, a, accy);
    }
    pkc = pkn;
  }
#pragma unroll
  for (int off = 8; off >= 1; off >>= 1) sm += __shfl_xor(sm, off, 64);  // per-head denom
  float inv = 1.0f / sm;
  float vx = accx * inv + bias[2 * lane];
  float vy = accy * inv + bias[2 * lane + 1];
  vx = vx > 0.f ? vx : expm1f(vx);
  vy = vy > 0.f ? vy : expm1f(vy);
  outf[(size_t)node * 64 + lane] = __floats2half2_rn(vx, vy);
}

// ===== fused softmax+agg H=1 (F=32): 16 lanes/node, pipelined stats =====
__global__ void gat_agg_h1(const int* __restrict__ rp, const unsigned* __restrict__ spk,
                           const __half2* __restrict__ Hf2, const float* __restrict__ alS,
                           const float* __restrict__ alD, const float* __restrict__ bias,
                           __half2* __restrict__ outf) {
  int node = (blockIdx.x * 256 + threadIdx.x) >> 4;
  int lane = threadIdx.x & 15;
  if (node >= NN) return;
  int beg = rp[node], end = rp[node + 1];
  float ad = alD[node];
  float sm = 0.f;
  auto mk = [&](int ch) -> unsigned {
    unsigned pk = (unsigned)node;
    if (lane < end - ch) {
      int sv = (int)(spk[ch + lane] & 0xFFFFu);
      float x = alS[sv] + ad;
      x = x > 0.f ? x : SLOPE * x;
      float ev = __expf(x);
      sm += ev;
      pk = ((unsigned)__half_as_ushort(__float2half(ev)) << 16) | (unsigned)sv;
    }
    return pk;
  };
  unsigned pkc = (beg < end) ? mk(beg) : (unsigned)node;
  float xsf = alS[node] + ad;
  xsf = xsf > 0.f ? xsf : SLOPE * xsf;
  float evs = __expf(xsf);
  __half2 hself = Hf2[(size_t)node * 16 + lane];
  float accx = __low2float(hself) * evs;
  float accy = __high2float(hself) * evs;
  if (lane == 0) sm += evs;
  for (int ch = beg; ch < end; ch += 16) {
    unsigned pkn = (ch + 16 < end) ? mk(ch + 16) : (unsigned)node;
    unsigned parr[16];
#pragma unroll
    for (int e = 0; e < 16; ++e) parr[e] = __shfl(pkc, e, 16);
    __half2 hv[16];
#pragma unroll
    for (int e = 0; e < 16; ++e)
      hv[e] = Hf2[(size_t)(parr[e] & 0xFFFFu) * 16 + lane];
#pragma unroll
    for (int e = 0; e < 16; ++e) {
      float a = __half2float(__ushort_as_half((unsigned short)(parr[e] >> 16)));
      float2 f = __half22float2(hv[e]);
      accx = fmaf(f.x, a, accx);
      accy = fmaf(f.y, a, accy);
    }
    pkc = pkn;
  }
#pragma unroll
  for (int off = 8; off >= 1; off >>= 1) sm += __shfl_xor(sm, off, 16);
  float inv = 1.0f / sm;
  float vx = accx * inv + bias[2 * lane];
  float vy = accy * inv + bias[2 * lane + 1];
  vx = vx > 0.f ? vx : expm1f(vx);
  vy = vy > 0.f ? vy : expm1f(vy);
  outf[(size_t)node * 16 + lane] = __floats2half2_rn(vx, vy);
}

// ======================= fused pool (sorted batch) + mu/logvar heads =======================
__device__ __forceinline__ int lb_batch(const int* __restrict__ b, int val) {
  int lo = 0, hi = NN;
  while (lo < hi) { int mid = (lo + hi) >> 1; if (b[mid] < val) lo = mid + 1; else hi = mid; }
  return lo;
}

__global__ void pool_head(const __half2* __restrict__ feat, const int* __restrict__ batch,
                          const float* __restrict__ Wmu, const float* __restrict__ bmu,
                          const float* __restrict__ Wlv, const float* __restrict__ blv,
                          float* __restrict__ out) {
  int g = blockIdx.x;
  int start = lb_batch(batch, g), end = lb_batch(batch, g + 1);
  int cp = threadIdx.x & 15, sub = threadIdx.x >> 4;
  float ax = 0.f, ay = 0.f;
  for (int n = start + sub; n < end; n += 16) {
    __half2 v = feat[(size_t)n * 16 + cp];
    ax += __low2float(v);
    ay += __high2float(v);
  }
  __shared__ float red[16][32];
  __shared__ float pl[32];
  red[sub][2 * cp] = ax;
  red[sub][2 * cp + 1] = ay;
  __syncthreads();
  if (threadIdx.x < 32) {
    float s = 0.f;
#pragma unroll
    for (int i = 0; i < 16; ++i) s += red[i][threadIdx.x];
    pl[threadIdx.x] = s / fmaxf((float)(end - start), 1.0f);
  }
  __syncthreads();
  if (threadIdx.x < NLAT) {
    int l = threadIdx.x;
    float mu = bmu[l], lv = blv[l];
#pragma unroll
    for (int k = 0; k < 32; ++k) {
      float p = pl[k];
      mu = fmaf(p, Wmu[k * NLAT + l], mu);
      lv = fmaf(p, Wlv[k * NLAT + l], lv);
    }
    out[g * NLAT + l] = mu;
    out[NG * NLAT + g * NLAT + l] = lv;
  }
}

extern "C" void kernel_launch(void* const* d_in, const int* in_sizes, int n_in,
                              void* d_out, int out_size, void* d_ws, size_t ws_size,
                              hipStream_t stream) {
  const float* x     = (const float*)d_in[0];
  const float* W1    = (const float*)d_in[1];
  const float* as1   = (const float*)d_in[2];
  const float* ad1   = (const float*)d_in[3];
  const float* b1    = (const float*)d_in[4];
  const float* W2    = (const float*)d_in[5];
  const float* as2   = (const float*)d_in[6];
  const float* ad2   = (const float*)d_in[7];
  const float* b2    = (const float*)d_in[8];
  const float* W3    = (const float*)d_in[9];
  const float* as3   = (const float*)d_in[10];
  const float* ad3   = (const float*)d_in[11];
  const float* b3    = (const float*)d_in[12];
  const float* Wmu   = (const float*)d_in[13];
  const float* bmu   = (const float*)d_in[14];
  const float* Wlv   = (const float*)d_in[15];
  const float* blv   = (const float*)d_in[16];
  const int*   ei    = (const int*)d_in[17];
  const int*   batch = (const int*)d_in[18];
  float* out = (float*)d_out;

  _Float16* A   = (_Float16*)d_ws;                  // [N,128] fp16 h (gemm out, flat)
  _Float16* Bh  = A + (size_t)NN * 128;             // [N,128] fp16 features
  float* alS    = (float*)(Bh + (size_t)NN * 128);  // [N,4]
  float* alD    = alS + (size_t)NN * 4;             // [N,4]
  _Float16* WT1 = (_Float16*)(alD + (size_t)NN * 4);// [128*128]
  _Float16* WT2 = WT1 + 16384;                      // [128*128]
  _Float16* WT3 = WT2 + 16384;                      // [32*128]
  int* rp       = (int*)(WT3 + 4096);               // [N+1]
  int* gcur     = rp + NN + 1;                      // [256]
  int* bbase    = gcur + 256;                       // [256]
  unsigned* gbuf = (unsigned*)(bbase + 256);        // [NBK*BCAP]
  unsigned* spk  = gbuf + (size_t)NBK * BCAP;       // [NE] packed (dlocal<<16|src)

  dim3 blk(256);

  // ---------------- CSR build + weight prep ----------------
  hipMemsetAsync(gcur, 0, 256 * sizeof(int), stream);
  p1_bucket<<<NB1, blk, 0, stream>>>(ei, gcur, gbuf);
  p2_sort<<<NBK, blk, 0, stream>>>(gbuf, gcur, bbase, rp, spk);
  wcast<<<144, blk, 0, stream>>>(W1, W2, W3, WT1, WT2, WT3);

  const int GB = (NN + 63) / 64;
  // ---------------- layer 1 (f32 x input) ----------------
  gemm_mfma<128, true><<<GB, blk, 0, stream>>>(x, WT1, as1, ad1, A, alS, alD);
  gat_agg_h4<<<(NN * 64) / 256, blk, 0, stream>>>(rp, spk, (const __half2*)A, alS, alD, b1, (__half2*)Bh);
  // ---------------- layer 2 ----------------
  gemm_mfma<128, false><<<GB, blk, 0, stream>>>(Bh, WT2, as2, ad2, A, alS, alD);
  gat_agg_h4<<<(NN * 64) / 256, blk, 0, stream>>>(rp, spk, (const __half2*)A, alS, alD, b2, (__half2*)Bh);
  // ---------------- layer 3 ----------------
  gemm_mfma<32, false><<<GB, blk, 0, stream>>>(Bh, WT3, as3, ad3, A, alS, alD);
  gat_agg_h1<<<(NN * 16) / 256, blk, 0, stream>>>(rp, spk, (const __half2*)A, alS, alD, b3, (__half2*)Bh);

  // ---------------- fused pool + heads ----------------
  pool_head<<<NG, blk, 0, stream>>>((const __half2*)Bh, batch, Wmu, bmu, Wlv, blv, out);
}